// Round 5
// baseline (176.753 us; speedup 1.0000x reference)
//
#include <hip/hip_runtime.h>
#include <hip/hip_bf16.h>
#include <stdint.h>

#define KDIM 4096
#define NDIM 4096
#define MDIM 4096
#define BM 256
#define BN 256
#define BK 64

typedef __attribute__((ext_vector_type(8))) short bf16x8;
typedef __attribute__((ext_vector_type(16))) float f32x16;

// ---------- helpers ----------

__device__ __forceinline__ unsigned short bf16bits(float f) {
    union { float f; uint32_t u; } c; c.f = f;
    uint32_t u = c.u;
    uint32_t r = (u + 0x7fffu + ((u >> 16) & 1u)) >> 16;   // RNE
    return (unsigned short)r;
}

// Faithful FP4 E2M1 quant-dequant (matches reference float math).
__device__ __forceinline__ float fp4qd(float x) {
    float a = fabsf(x);
    if (a == 0.0f) return 0.0f;
    float e = floorf(log2f(a));
    float val;
    if (e < 0.0f) {                       // subnormal path
        float mant = fminf(fmaxf(rintf(a * 2.0f), 0.0f), 1.0f);
        val = mant * 0.5f;
    } else {
        float ec = fminf(e, 2.0f);
        float p  = exp2f(ec);             // exact: 1,2,4
        float mant = fminf(fmaxf(rintf((a / p - 1.0f) * 2.0f), 0.0f), 1.0f);
        val = (1.0f + 0.5f * mant) * p;
    }
    return (x < 0.0f) ? -val : val;
}

__device__ __forceinline__ void gld16(void* lds, const void* g) {
    __builtin_amdgcn_global_load_lds(
        (const __attribute__((address_space(1))) unsigned int*)g,
        (__attribute__((address_space(3))) unsigned int*)lds,
        16, 0, 0);
}

// ---------- kernel 1: weight quant-dequant -> bf16 ----------
__global__ __launch_bounds__(256) void wdeq_kernel(const float* __restrict__ W,
                                                   unsigned short* __restrict__ Wq) {
    int grp = blockIdx.x * 4 + (threadIdx.x >> 6);
    int l = threadIdx.x & 63;
    const float* gp = W + (size_t)grp * 128 + l * 2;
    float2 v = *(const float2*)gp;
    float am = fmaxf(fabsf(v.x), fabsf(v.y));
    #pragma unroll
    for (int s = 32; s; s >>= 1) am = fmaxf(am, __shfl_xor(am, s));
    float scale = (am == 0.0f) ? 1.0f : am / 6.0f;
    float q0 = fp4qd(v.x / scale) * scale;
    float q1 = fp4qd(v.y / scale) * scale;
    ushort2 o;
    o.x = bf16bits(q0);
    o.y = bf16bits(q1);
    *(ushort2*)(Wq + (size_t)grp * 128 + l * 2) = o;
}

// ---------- kernel 2: x f32 -> bf16 ----------
__global__ __launch_bounds__(256) void xcvt_kernel(const float* __restrict__ X,
                                                   unsigned short* __restrict__ Xb) {
    size_t i = (size_t)(blockIdx.x * 256 + threadIdx.x) * 4;
    float4 v = *(const float4*)(X + i);
    ushort4 o;
    o.x = bf16bits(v.x); o.y = bf16bits(v.y);
    o.z = bf16bits(v.z); o.w = bf16bits(v.w);
    *(ushort4*)(Xb + i) = o;
}

// ---------- kernel 3: 256x256 8-phase GEMM, 32x32x16 MFMA ----------
// C = A @ B^T + bias. 8 waves (2M x 4N), per-wave 128x64 out =
// 4 m-frags x 2 n-frags of 32x32, acc[4][2] f32x16 (128 VGPR).
// LDS: smem[buf][op][half(128 rows)][128B rows], 128 KiB, chunk-XOR swizzle
// (slot = chunk ^ (row&7)); conflict-free ds_read_b128.
// A-frag (32x32x16): lane l -> row = l&31, k = (l>>5)*8 + i  (16B read at
// chunk kc*2 + (l>>5)). C/D: col = l&31, row = (q&3)+8*(q>>2)+4*(l>>5).
// Schedule = R2 skeleton (best measured): 8 phases / 2 K-tiles, quadrants
// (0,0)(0,1)(1,1)(1,0); stage 1 half-tile (2 gld16) per phase;
// vmcnt(4) at P4/P8 only (FIFO: drains the buffer needed next phase).

#define BAR()    __builtin_amdgcn_s_barrier()
#define LGKM0()  asm volatile("s_waitcnt lgkmcnt(0)" ::: "memory")
#define VM4()    asm volatile("s_waitcnt vmcnt(4)" ::: "memory")
#define SCH0()   __builtin_amdgcn_sched_barrier(0)
#define PRIO(x)  __builtin_amdgcn_s_setprio(x)
#define MFMA32(a, b, c) __builtin_amdgcn_mfma_f32_32x32x16_bf16(a, b, c, 0, 0, 0)

__global__ __launch_bounds__(512, 2) void gemm256(const unsigned short* __restrict__ A,
                                                  const unsigned short* __restrict__ B,
                                                  const float* __restrict__ bias,
                                                  float* __restrict__ C) {
    __shared__ __attribute__((aligned(16))) char smem[2][2][2][16384];
    char* sm = (char*)&smem[0][0][0][0];

    const int t = threadIdx.x;
    const int l = t & 63;
    const int w = __builtin_amdgcn_readfirstlane(t >> 6);  // 0..7
    const int wm = w >> 2;        // 0..1  (M half)
    const int wn = w & 3;         // 0..3  (N quarter)

    // bijective XCD swizzle (256 blocks, 8 XCDs)
    int bid = blockIdx.x;
    int swz = (bid & 7) * 32 + (bid >> 3);
    int brow = (swz >> 4) * BM;
    int bcol = (swz & 15) * BN;

    // ---- staging addresses (pre-swizzled global source, linear LDS dest) ----
    const int lr8  = l >> 3;                 // row in 8-row slab
    const int slot = l & 7;
    const int scol = (slot ^ lr8) << 3;      // swizzled source col (elements)
    const unsigned short* pA = A + (size_t)(brow + w * 8 + lr8) * KDIM + scol;
    const unsigned short* pB = B + (size_t)(bcol + w * 8 + lr8) * KDIM + scol;

    // stage one half-tile: op 0=A 1=B, half h, buffer b, K-tile kt (2 gld16)
#define STAGE(b, op, h, kt) do {                                               \
    const unsigned short* _s = ((op) ? pB : pA)                                \
        + (size_t)(h) * 128 * KDIM + (size_t)(kt) * BK;                        \
    gld16(sm + (b) * 65536 + (op) * 32768 + (h) * 16384 + w * 1024, _s);       \
    gld16(sm + (b) * 65536 + (op) * 32768 + (h) * 16384 + 8192 + w * 1024,     \
          _s + (size_t)64 * KDIM);                                             \
} while (0)

    // ---- fragment read addressing (32x32x16) ----
    const int l31 = l & 31;
    const int l7  = l & 7;
    const int hi  = l >> 5;                  // 0..1
    // swizzled 16B-chunk byte offsets for kc=0..3 (global chunk = kc*2 + hi)
    const int kcx0 = (((0 * 2 + hi) ^ l7) << 4);
    const int kcx1 = (((1 * 2 + hi) ^ l7) << 4);
    const int kcx2 = (((2 * 2 + hi) ^ l7) << 4);
    const int kcx3 = (((3 * 2 + hi) ^ l7) << 4);
    const int rowb = l31 * 128;
    // B lane row within op-1 region: wn*64 + nf*32 + l31 (half = wn>>1)
    const int bBbase = 32768 + (wn >> 1) * 16384 + ((wn & 1) * 64) * 128 + rowb;
    const int aAbase = wm * 16384 + rowb;

#define RD_A32(b, mh) do {                                                      \
    const char* _p = sm + (b) * 65536 + aAbase + (mh) * 8192;                   \
    _Pragma("unroll")                                                           \
    for (int mm = 0; mm < 2; ++mm) {                                            \
        av[mm][0] = *(const bf16x8*)(_p + mm * 4096 + kcx0);                    \
        av[mm][1] = *(const bf16x8*)(_p + mm * 4096 + kcx1);                    \
        av[mm][2] = *(const bf16x8*)(_p + mm * 4096 + kcx2);                    \
        av[mm][3] = *(const bf16x8*)(_p + mm * 4096 + kcx3);                    \
    }                                                                           \
} while (0)

#define RD_B32(b, nf, arr) do {                                                 \
    const char* _p = sm + (b) * 65536 + bBbase + (nf) * 4096;                   \
    arr[0] = *(const bf16x8*)(_p + kcx0);                                       \
    arr[1] = *(const bf16x8*)(_p + kcx1);                                       \
    arr[2] = *(const bf16x8*)(_p + kcx2);                                       \
    arr[3] = *(const bf16x8*)(_p + kcx3);                                       \
} while (0)

    // 8 MFMA per phase: kc-outer, mm-inner (2 independent acc chains)
#define MM32(mh, nh, B_)                                                        \
    _Pragma("unroll")                                                           \
    for (int kc = 0; kc < 4; ++kc)                                              \
        _Pragma("unroll")                                                       \
        for (int mm = 0; mm < 2; ++mm)                                          \
            acc[(mh) * 2 + mm][nh] =                                            \
                MFMA32(av[mm][kc], B_[kc], acc[(mh) * 2 + mm][nh]);

    f32x16 acc[4][2];
    #pragma unroll
    for (int m = 0; m < 4; ++m)
        #pragma unroll
        for (int n = 0; n < 2; ++n)
            #pragma unroll
            for (int q = 0; q < 16; ++q)
                acc[m][n][q] = 0.f;

    bf16x8 av[2][4], bvA[4], bvB[4];

    // ---- prologue: tile0 full (8 gld) + t1.B0 + t1.A0 (4 gld) ----
    STAGE(0, 0, 0, 0); STAGE(0, 0, 1, 0); STAGE(0, 1, 0, 0); STAGE(0, 1, 1, 0);
    STAGE(1, 1, 0, 1); STAGE(1, 0, 0, 1);
    VM4();            // tile0 landed; t1.B0/A0 in flight
    BAR(); SCH0();

    // ---- main loop: iter computes K-tiles 2it (buf0) and 2it+1 (buf1) ----
    for (int it = 0; it < 32; ++it) {
        const int k1 = 2 * it + 1;
        const int k2 = (2 * it + 2) & 63;   // wrap on last iter (never read)
        const int k3 = (2 * it + 3) & 63;

        // P1: read buf0 A-mh0 + B-nf0 ; stage t1.A1
        RD_A32(0, 0); RD_B32(0, 0, bvA); STAGE(1, 0, 1, k1);
        BAR(); LGKM0(); SCH0(); PRIO(1); MM32(0, 0, bvA); PRIO(0); BAR(); SCH0();
        // P2: read buf0 B-nf1 ; stage t1.B1
        RD_B32(0, 1, bvB); STAGE(1, 1, 1, k1);
        BAR(); LGKM0(); SCH0(); PRIO(1); MM32(0, 1, bvB); PRIO(0); BAR(); SCH0();
        // P3: read buf0 A-mh1 ; stage t2.B0
        RD_A32(0, 1); STAGE(0, 1, 0, k2);
        BAR(); LGKM0(); SCH0(); PRIO(1); MM32(1, 1, bvB); PRIO(0); BAR(); SCH0();
        // P4: stage t2.A0 ; counted vmcnt -> buf1 (t1) fully landed
        STAGE(0, 0, 0, k2);
        BAR(); SCH0(); PRIO(1); MM32(1, 0, bvA); PRIO(0); VM4(); BAR(); SCH0();

        // P5: read buf1 A-mh0 + B-nf0 ; stage t2.A1
        RD_A32(1, 0); RD_B32(1, 0, bvA); STAGE(0, 0, 1, k2);
        BAR(); LGKM0(); SCH0(); PRIO(1); MM32(0, 0, bvA); PRIO(0); BAR(); SCH0();
        // P6: read buf1 B-nf1 ; stage t2.B1
        RD_B32(1, 1, bvB); STAGE(0, 1, 1, k2);
        BAR(); LGKM0(); SCH0(); PRIO(1); MM32(0, 1, bvB); PRIO(0); BAR(); SCH0();
        // P7: read buf1 A-mh1 ; stage t3.B0
        RD_A32(1, 1); STAGE(1, 1, 0, k3);
        BAR(); LGKM0(); SCH0(); PRIO(1); MM32(1, 1, bvB); PRIO(0); BAR(); SCH0();
        // P8: stage t3.A0 ; counted vmcnt -> buf0 (t2) fully landed
        STAGE(1, 0, 0, k3);
        BAR(); SCH0(); PRIO(1); MM32(1, 0, bvA); PRIO(0); VM4(); BAR(); SCH0();
    }

    // ---- epilogue: C[row][col] = acc + bias[col] ----
    // 32x32 C/D: col = l&31, row = (q&3) + 8*(q>>2) + 4*(l>>5)
    float bb[2];
    #pragma unroll
    for (int n = 0; n < 2; ++n) bb[n] = bias[bcol + wn * 64 + n * 32 + l31];
    #pragma unroll
    for (int mi = 0; mi < 4; ++mi) {
        #pragma unroll
        for (int q = 0; q < 16; ++q) {
            int row = brow + wm * 128 + mi * 32 + (q & 3) + 8 * (q >> 2) + 4 * hi;
            float* crow = C + (size_t)row * NDIM + bcol + wn * 64;
            #pragma unroll
            for (int n = 0; n < 2; ++n)
                crow[n * 32 + l31] = acc[mi][n][q] + bb[n];
        }
    }
}

// ---------- launch ----------
extern "C" void kernel_launch(void* const* d_in, const int* in_sizes, int n_in,
                              void* d_out, int out_size, void* d_ws, size_t ws_size,
                              hipStream_t stream) {
    const float* x = (const float*)d_in[0];
    const float* w = (const float*)d_in[1];
    const float* b = (const float*)d_in[2];
    float* out = (float*)d_out;

    unsigned short* xb = (unsigned short*)d_ws;                         // 32 MB
    unsigned short* wq = xb + (size_t)NDIM * KDIM;                      // 32 MB

    xcvt_kernel<<<MDIM * KDIM / 4 / 256, 256, 0, stream>>>(x, xb);
    wdeq_kernel<<<NDIM * (KDIM / 128) / 4, 256, 0, stream>>>(w, wq);
    gemm256<<<(MDIM / BM) * (NDIM / BN), 512, 0, stream>>>(xb, wq, b, out);
}

// Round 6
// 150.014 us; speedup vs baseline: 1.1782x; 1.1782x over previous
//
#include <hip/hip_runtime.h>
#include <hip/hip_bf16.h>
#include <stdint.h>

#define KDIM 4096
#define NDIM 4096
#define MDIM 4096
#define BM 256
#define BN 256
#define BK 64

typedef __attribute__((ext_vector_type(8))) short bf16x8;
typedef __attribute__((ext_vector_type(4))) float f32x4;

// ---------- helpers ----------

__device__ __forceinline__ unsigned short bf16bits(float f) {
    union { float f; uint32_t u; } c; c.f = f;
    uint32_t u = c.u;
    uint32_t r = (u + 0x7fffu + ((u >> 16) & 1u)) >> 16;   // RNE
    return (unsigned short)r;
}

// Faithful FP4 E2M1 quant-dequant (matches reference float math).
__device__ __forceinline__ float fp4qd(float x) {
    float a = fabsf(x);
    if (a == 0.0f) return 0.0f;
    float e = floorf(log2f(a));
    float val;
    if (e < 0.0f) {                       // subnormal path
        float mant = fminf(fmaxf(rintf(a * 2.0f), 0.0f), 1.0f);
        val = mant * 0.5f;
    } else {
        float ec = fminf(e, 2.0f);
        float p  = exp2f(ec);             // exact: 1,2,4
        float mant = fminf(fmaxf(rintf((a / p - 1.0f) * 2.0f), 0.0f), 1.0f);
        val = (1.0f + 0.5f * mant) * p;
    }
    return (x < 0.0f) ? -val : val;
}

__device__ __forceinline__ void gld16(void* lds, const void* g) {
    __builtin_amdgcn_global_load_lds(
        (const __attribute__((address_space(1))) unsigned int*)g,
        (__attribute__((address_space(3))) unsigned int*)lds,
        16, 0, 0);
}

// ---------- fused prep: x f32->bf16  +  weight fp4-quant-dequant->bf16 ----
// blocks [0, 16384): xcvt (256 thr x float4)
// blocks [16384, 32768): wdeq (4 waves x 2 groups/wave, float4 loads)
__global__ __launch_bounds__(256) void prep_kernel(const float* __restrict__ X,
                                                   const float* __restrict__ W,
                                                   unsigned short* __restrict__ Xb,
                                                   unsigned short* __restrict__ Wq) {
    int bid = blockIdx.x;
    int tid = threadIdx.x;
    if (bid < 16384) {
        size_t i = ((size_t)bid * 256 + tid) * 4;
        float4 v = *(const float4*)(X + i);
        ushort4 o;
        o.x = bf16bits(v.x); o.y = bf16bits(v.y);
        o.z = bf16bits(v.z); o.w = bf16bits(v.w);
        *(ushort4*)(Xb + i) = o;
    } else {
        // each wave: 64 lanes x 4 elems = 256 elems = 2 groups of 128
        size_t base = ((size_t)(bid - 16384) * 256 + tid) * 4;
        float4 v = *(const float4*)(W + base);
        float am = fmaxf(fmaxf(fabsf(v.x), fabsf(v.y)),
                         fmaxf(fabsf(v.z), fabsf(v.w)));
        #pragma unroll
        for (int s = 16; s; s >>= 1) am = fmaxf(am, __shfl_xor(am, s));  // 32-lane group
        float scale = (am == 0.0f) ? 1.0f : am / 6.0f;
        ushort4 o;
        o.x = bf16bits(fp4qd(v.x / scale) * scale);
        o.y = bf16bits(fp4qd(v.y / scale) * scale);
        o.z = bf16bits(fp4qd(v.z / scale) * scale);
        o.w = bf16bits(fp4qd(v.w / scale) * scale);
        *(ushort4*)(Wq + base) = o;
    }
}

// ---------- GEMM: 256x256-tile 8-phase, 16x16x32 MFMA (R2 skeleton) -------
// C = A @ B^T + bias. 8 waves (2M x 4N), per-wave 128x64, acc[8][4].
// LDS: smem[buf][op][half][16KB], 128 KiB. Half-tile staged via 2x gld16,
// chunk-XOR swizzle (slot = kc ^ (row&7)); conflict-free ds_read_b128.
// Read-rebalance vs R2: B-nh0 (4 reads) issued at P4/P8 tail after VM4
// (its region provably landed by that drain); phases now 8/4/8/4 reads.
// vmcnt(4) at P4/P8 only (FIFO: drains exactly the buffer needed next).

#define BAR()    __builtin_amdgcn_s_barrier()
#define LGKM0()  asm volatile("s_waitcnt lgkmcnt(0)" ::: "memory")
#define VM4()    asm volatile("s_waitcnt vmcnt(4)" ::: "memory")
#define SCH0()   __builtin_amdgcn_sched_barrier(0)
#define PRIO(x)  __builtin_amdgcn_s_setprio(x)

__global__ __launch_bounds__(512, 2) void gemm256(const unsigned short* __restrict__ A,
                                                  const unsigned short* __restrict__ B,
                                                  const float* __restrict__ bias,
                                                  float* __restrict__ C) {
    __shared__ __attribute__((aligned(16))) char smem[2][2][2][16384];
    char* sm = (char*)&smem[0][0][0][0];

    const int t = threadIdx.x;
    const int l = t & 63;
    const int w = __builtin_amdgcn_readfirstlane(t >> 6);  // 0..7
    const int wm = w >> 2;        // 0..1  (M half)
    const int wn = w & 3;         // 0..3  (N quarter)

    // bijective XCD swizzle (256 blocks, 8 XCDs)
    int bid = blockIdx.x;
    int swz = (bid & 7) * 32 + (bid >> 3);
    int brow = (swz >> 4) * BM;
    int bcol = (swz & 15) * BN;

    // ---- staging addresses (pre-swizzled global source, linear LDS dest) ----
    const int lr8  = l >> 3;                 // row in 8-row slab
    const int slot = l & 7;
    const int scol = (slot ^ lr8) << 3;      // swizzled source col (elements)
    const unsigned short* pA = A + (size_t)(brow + w * 8 + lr8) * KDIM + scol;
    const unsigned short* pB = B + (size_t)(bcol + w * 8 + lr8) * KDIM + scol;

    // stage one half-tile: op 0=A 1=B, half h, buffer b, K-tile kt (2 gld16)
#define STAGE(b, op, h, kt) do {                                               \
    const unsigned short* _s = ((op) ? pB : pA)                                \
        + (size_t)(h) * 128 * KDIM + (size_t)(kt) * BK;                        \
    gld16(sm + (b) * 65536 + (op) * 32768 + (h) * 16384 + w * 1024, _s);       \
    gld16(sm + (b) * 65536 + (op) * 32768 + (h) * 16384 + 8192 + w * 1024,     \
          _s + (size_t)64 * KDIM);                                             \
} while (0)

    // ---- fragment read addressing ----
    const int fr  = l & 15;
    const int fq  = l >> 4;
    const int kx0 = ((fq    ) ^ (fr & 7)) << 4;   // ks=0 swizzled chunk byte
    const int kx1 = ((fq + 4) ^ (fr & 7)) << 4;   // ks=1
    const int frA = fr * 128;

#define RD_A(b, mh) do {                                                        \
    const char* _p = sm + (b) * 65536 + wm * 16384 + (mh) * 8192 + frA;         \
    _Pragma("unroll")                                                           \
    for (int m = 0; m < 4; ++m) {                                               \
        av[m][0] = *(const bf16x8*)(_p + m * 2048 + kx0);                       \
        av[m][1] = *(const bf16x8*)(_p + m * 2048 + kx1);                       \
    }                                                                           \
} while (0)

#define RD_B(b, nh, arr) do {                                                   \
    const char* _p = sm + (b) * 65536 + 32768 + wn * 8192 + (nh) * 4096 + frA;  \
    _Pragma("unroll")                                                           \
    for (int n = 0; n < 2; ++n) {                                               \
        arr[n][0] = *(const bf16x8*)(_p + n * 2048 + kx0);                      \
        arr[n][1] = *(const bf16x8*)(_p + n * 2048 + kx1);                      \
    }                                                                           \
} while (0)

#define MM(mh, nh, B_)                                                          \
    _Pragma("unroll")                                                           \
    for (int m = 0; m < 4; ++m)                                                 \
        _Pragma("unroll")                                                       \
        for (int n = 0; n < 2; ++n)                                             \
            _Pragma("unroll")                                                   \
            for (int ks = 0; ks < 2; ++ks)                                      \
                acc[(mh) * 4 + m][(nh) * 2 + n] =                               \
                    __builtin_amdgcn_mfma_f32_16x16x32_bf16(                    \
                        av[m][ks], B_[n][ks], acc[(mh) * 4 + m][(nh) * 2 + n],  \
                        0, 0, 0);

    f32x4 acc[8][4];
    #pragma unroll
    for (int m = 0; m < 8; ++m)
        #pragma unroll
        for (int n = 0; n < 4; ++n)
            acc[m][n] = f32x4{0.f, 0.f, 0.f, 0.f};

    bf16x8 av[4][2], bvA[2][2], bvB[2][2];

    // ---- prologue: tile0 full (8 gld) + t1.B0 + t1.A0 (4 gld) ----
    STAGE(0, 0, 0, 0); STAGE(0, 0, 1, 0); STAGE(0, 1, 0, 0); STAGE(0, 1, 1, 0);
    STAGE(1, 1, 0, 1); STAGE(1, 0, 0, 1);
    VM4();            // tile0 landed; t1.B0/A0 in flight
    BAR();
    RD_B(0, 0, bvA);  // pre-read t0.B0 (consumed P1, P4)
    SCH0();

    // ---- main loop: iter computes K-tiles 2it (buf0) and 2it+1 (buf1) ----
    for (int it = 0; it < 32; ++it) {
        const int k1 = 2 * it + 1;
        const int k2 = (2 * it + 2) & 63;   // wrap on last iter (never read)
        const int k3 = (2 * it + 3) & 63;

        // P1: read buf0 A-mh0 (8) ; stage t1.A1
        RD_A(0, 0); STAGE(1, 0, 1, k1);
        BAR(); LGKM0(); SCH0(); PRIO(1); MM(0, 0, bvA); PRIO(0); BAR(); SCH0();
        // P2: read buf0 B-nh1 (4) ; stage t1.B1
        RD_B(0, 1, bvB); STAGE(1, 1, 1, k1);
        BAR(); LGKM0(); SCH0(); PRIO(1); MM(0, 1, bvB); PRIO(0); BAR(); SCH0();
        // P3: read buf0 A-mh1 (8) ; stage t2.B0
        RD_A(0, 1); STAGE(0, 1, 0, k2);
        BAR(); LGKM0(); SCH0(); PRIO(1); MM(1, 1, bvB); PRIO(0); BAR(); SCH0();
        // P4: stage t2.A0 ; VM4 -> buf1 landed ; tail-read buf1.B0 (4)
        STAGE(0, 0, 0, k2);
        BAR(); SCH0(); PRIO(1); MM(1, 0, bvA); PRIO(0);
        VM4(); RD_B(1, 0, bvA);
        BAR(); SCH0();

        // P5: read buf1 A-mh0 (8) ; stage t2.A1
        RD_A(1, 0); STAGE(0, 0, 1, k2);
        BAR(); LGKM0(); SCH0(); PRIO(1); MM(0, 0, bvA); PRIO(0); BAR(); SCH0();
        // P6: read buf1 B-nh1 (4) ; stage t2.B1
        RD_B(1, 1, bvB); STAGE(0, 1, 1, k2);
        BAR(); LGKM0(); SCH0(); PRIO(1); MM(0, 1, bvB); PRIO(0); BAR(); SCH0();
        // P7: read buf1 A-mh1 (8) ; stage t3.B0
        RD_A(1, 1); STAGE(1, 1, 0, k3);
        BAR(); LGKM0(); SCH0(); PRIO(1); MM(1, 1, bvB); PRIO(0); BAR(); SCH0();
        // P8: stage t3.A0 ; VM4 -> buf0 (t2) landed ; tail-read buf0.B0 (4)
        STAGE(1, 0, 0, k3);
        BAR(); SCH0(); PRIO(1); MM(1, 0, bvA); PRIO(0);
        VM4(); RD_B(0, 0, bvA);
        BAR(); SCH0();
    }

    // ---- epilogue: C[row][col] = acc + bias[col] ----
    // C/D layout: col = lane&15, row = (lane>>4)*4 + reg
    float bb[4];
    #pragma unroll
    for (int n = 0; n < 4; ++n) bb[n] = bias[bcol + wn * 64 + n * 16 + fr];
    #pragma unroll
    for (int mi = 0; mi < 8; ++mi) {
        #pragma unroll
        for (int q = 0; q < 4; ++q) {
            int row = brow + wm * 128 + mi * 16 + fq * 4 + q;
            float* crow = C + (size_t)row * NDIM + bcol + wn * 64;
            #pragma unroll
            for (int n = 0; n < 4; ++n)
                crow[n * 16 + fr] = acc[mi][n][q] + bb[n];
        }
    }
}

// ---------- launch ----------
extern "C" void kernel_launch(void* const* d_in, const int* in_sizes, int n_in,
                              void* d_out, int out_size, void* d_ws, size_t ws_size,
                              hipStream_t stream) {
    const float* x = (const float*)d_in[0];
    const float* w = (const float*)d_in[1];
    const float* b = (const float*)d_in[2];
    float* out = (float*)d_out;

    unsigned short* xb = (unsigned short*)d_ws;                         // 32 MB
    unsigned short* wq = xb + (size_t)NDIM * KDIM;                      // 32 MB

    prep_kernel<<<32768, 256, 0, stream>>>(x, w, xb, wq);
    gemm256<<<(MDIM / BM) * (NDIM / BN), 512, 0, stream>>>(xb, wq, b, out);
}